// Round 3
// baseline (214.390 us; speedup 1.0000x reference)
//
#include <hip/hip_runtime.h>

constexpr int S_LEN = 2048;
constexpr int D_K   = 64;
constexpr int N_BH  = 32;   // B*H
constexpr int KB    = 64;   // k per chunk

typedef __attribute__((ext_vector_type(8))) short short8;
typedef __attribute__((ext_vector_type(4))) float f32x4;
typedef unsigned short ushort_t;

__device__ __forceinline__ unsigned short f2bf(float f) {
    unsigned int u = __builtin_bit_cast(unsigned int, f);
    u += 0x7fffu + ((u >> 16) & 1u);          // round-to-nearest-even
    return (unsigned short)(u >> 16);
}
__device__ __forceinline__ float bf2f(unsigned short h) {
    unsigned int u = ((unsigned int)h) << 16;
    return __builtin_bit_cast(float, u);
}

// ============================ prep kernels ============================
__global__ __launch_bounds__(256)
void prep_k(const float* __restrict__ K, ushort_t* __restrict__ Kws) {
    const int idx = blockIdx.x * 256 + threadIdx.x;
    const float4* src = (const float4*)K + (size_t)idx * 2;
    float4 a = src[0], b = src[1];
    float x[8] = {a.x, a.y, a.z, a.w, b.x, b.y, b.z, b.w};
    short8 o;
    #pragma unroll
    for (int j = 0; j < 8; ++j) o[j] = (short)f2bf(x[j] * 0.125f);
    *(short8*)(Kws + (size_t)idx * 8) = o;
}

__global__ __launch_bounds__(256)
void prep_v(const float* __restrict__ V, ushort_t* __restrict__ Vws) {
    const int gid = blockIdx.x * 256 + threadIdx.x;
    const int u   = gid & 511;
    const int bc  = gid >> 9;
    const int c   = bc & 31;
    const int bh  = bc >> 5;
    const int kg  = u >> 6;
    const int d   = u & 63;
    const float* vp = V + ((size_t)bh * S_LEN + c * KB + kg * 8) * D_K + d;
    short8 o;
    #pragma unroll
    for (int i = 0; i < 8; ++i) o[i] = (short)f2bf(vp[(size_t)i * D_K]);
    *(short8*)(Vws + ((size_t)(bh * 32 + c) * D_K + d) * KB + kg * 8) = o;
}

// ============================ main kernel =============================
// 512 threads = 8 waves; QB = 128 q rows/block.
// K/V LDS tiles [64][64] bf16, XOR-swizzled: byte = row*128 + (colbyte ^ ((row&7)<<4))
// Plds per-wave [16][64] bf16, same swizzle family.
__global__ __launch_bounds__(512, 4)
void sdpa_main(const float* __restrict__ Q, const ushort_t* __restrict__ Kws,
               const ushort_t* __restrict__ Vws, float* __restrict__ out)
{
    __shared__ __align__(16) ushort_t Kbuf[2][4096];
    __shared__ __align__(16) ushort_t Vbuf[2][4096];
    __shared__ __align__(16) ushort_t Plds[8][2048];

    const int tid = threadIdx.x;
    const int w   = tid >> 6;
    const int l   = tid & 63;
    const int lr  = l & 15;
    const int lh  = l >> 4;

    // balanced remap: CU slot pairs (r, 15-r) -> every CU does equal chunk-units
    const int b    = blockIdx.x;         // 0..511
    const int s    = b >> 8;
    const int cidx = b & 255;
    const int rmap = cidx & 7;
    const int bh   = cidx >> 3;
    const int qblk = s ? (15 - rmap) : rmap;
    const int q0   = qblk * 128;
    const int qw   = q0 + w * 16;
    const int nch  = 2 * (qblk + 1);     // always even, >= 2

    float* ctx_out  = out;
    float* attn_out = out + (size_t)N_BH * S_LEN * D_K;

    // Q fragments, hi/lo bf16 split
    short8 qhi[2], qlo[2];
    {
        const float* qrow = Q + ((size_t)bh * S_LEN + qw + lr) * D_K;
        #pragma unroll
        for (int ds = 0; ds < 2; ++ds) {
            const float4* p4 = (const float4*)(qrow + ds * 32 + lh * 8);
            float4 a = p4[0], bq = p4[1];
            float x[8] = {a.x, a.y, a.z, a.w, bq.x, bq.y, bq.z, bq.w};
            short8 hi, lo;
            #pragma unroll
            for (int j = 0; j < 8; ++j) {
                unsigned short h = f2bf(x[j]);
                hi[j] = (short)h;
                lo[j] = (short)f2bf(x[j] - bf2f(h));
            }
            qhi[ds] = hi; qlo[ds] = lo;
        }
    }

    const short8* Kt  = (const short8*)(Kws + (size_t)bh * S_LEN * D_K);
    const short8* Vt8 = (const short8*)(Vws + (size_t)bh * 32 * 4096);

    const int wrow  = tid >> 3;
    const int wcol  = (tid & 7) << 4;
    const int wphys = wrow * 128 + (wcol ^ ((wrow & 7) << 4));
    const int rsw   = (lr & 7) << 4;     // frag-read swizzle

    // ================= PASS 1: row sums =================
    float inv_[4];
    {
        float sum[4] = {0.f, 0.f, 0.f, 0.f};

        auto p1 = [&](const ushort_t* Kbp, int c) {
            const char* Kb = (const char*)Kbp;
            __builtin_amdgcn_s_setprio(1);
            #pragma unroll
            for (int nt = 0; nt < 4; ++nt) {
                f32x4 acc = {0.f, 0.f, 0.f, 0.f};
                #pragma unroll
                for (int ks = 0; ks < 2; ++ks) {
                    short8 bk = *(const short8*)(Kb + (nt * 16 + lr) * 128 + ((ks * 64 + lh * 16) ^ rsw));
                    acc = __builtin_amdgcn_mfma_f32_16x16x32_bf16(qhi[ks], bk, acc, 0, 0, 0);
                    acc = __builtin_amdgcn_mfma_f32_16x16x32_bf16(qlo[ks], bk, acc, 0, 0, 0);
                }
                const int kg = c * KB + nt * 16 + lr;
                #pragma unroll
                for (int rr = 0; rr < 4; ++rr) {
                    if (kg <= qw + lh * 4 + rr)
                        sum[rr] += __expf(fminf(acc[rr], 60.f));
                }
            }
            __builtin_amdgcn_s_setprio(0);
        };

        short8 kA = Kt[tid];
        short8 kB = Kt[512 + tid];
        *(short8*)((char*)&Kbuf[0][0] + wphys) = kA;
        __syncthreads();
        for (int c = 0; c < nch; c += 2) {
            if (c + 2 < nch) kA = Kt[(c + 2) * 512 + tid];
            p1(&Kbuf[0][0], c);
            *(short8*)((char*)&Kbuf[1][0] + wphys) = kB;   // data for chunk c+1
            __syncthreads();
            if (c + 3 < nch) kB = Kt[(c + 3) * 512 + tid];
            p1(&Kbuf[1][0], c + 1);
            if (c + 2 < nch) *(short8*)((char*)&Kbuf[0][0] + wphys) = kA;
            __syncthreads();
        }
        #pragma unroll
        for (int rr = 0; rr < 4; ++rr) {
            float t = sum[rr];
            t += __shfl_xor(t, 1);
            t += __shfl_xor(t, 2);
            t += __shfl_xor(t, 4);
            t += __shfl_xor(t, 8);
            inv_[rr] = 1.f / t;
        }
    }

    // ================= PASS 2: attn write + PV =================
    f32x4 ctx[4];
    #pragma unroll
    for (int nt = 0; nt < 4; ++nt) ctx[nt] = (f32x4){0.f, 0.f, 0.f, 0.f};

    // store-path lane mapping: 4 lanes per q row, 16 consecutive k per lane
    const int sqr = l >> 2;          // 0..15: local q row
    const int sm  = l & 3;           // 0..3 : 16-float k segment
    float* srowp = attn_out + ((size_t)bh * S_LEN + qw + sqr) * S_LEN;

    {
        auto p2 = [&](const ushort_t* Kbp, const ushort_t* Vbp, int c) {
            const char* Kb = (const char*)Kbp;
            const char* Vb = (const char*)Vbp;
            // QK^T + exp + stage normalized P (bf16) into Plds
            #pragma unroll
            for (int nt = 0; nt < 4; ++nt) {
                f32x4 acc = {0.f, 0.f, 0.f, 0.f};
                __builtin_amdgcn_s_setprio(1);
                #pragma unroll
                for (int ks = 0; ks < 2; ++ks) {
                    short8 bk = *(const short8*)(Kb + (nt * 16 + lr) * 128 + ((ks * 64 + lh * 16) ^ rsw));
                    acc = __builtin_amdgcn_mfma_f32_16x16x32_bf16(qhi[ks], bk, acc, 0, 0, 0);
                    acc = __builtin_amdgcn_mfma_f32_16x16x32_bf16(qlo[ks], bk, acc, 0, 0, 0);
                }
                __builtin_amdgcn_s_setprio(0);
                const int kg = c * KB + nt * 16 + lr;
                #pragma unroll
                for (int rr = 0; rr < 4; ++rr) {
                    const int pwr = lh * 4 + rr;
                    const int qg  = qw + pwr;
                    float p = (kg <= qg) ? __expf(fminf(acc[rr], 60.f)) * inv_[rr] : 0.f;
                    Plds[w][pwr * 64 + ((nt * 16 + lr) ^ ((pwr & 7) << 3))] = f2bf(p);
                }
            }
            // PV: A-frag from Plds (row=lr, k=ks*32+lh*8)
            __builtin_amdgcn_s_setprio(1);
            #pragma unroll
            for (int ks = 0; ks < 2; ++ks) {
                short8 pa = *(const short8*)&Plds[w][lr * 64 + ((ks * 32 + lh * 8) ^ ((lr & 7) << 3))];
                #pragma unroll
                for (int nt = 0; nt < 4; ++nt) {
                    short8 vb = *(const short8*)(Vb + (nt * 16 + lr) * 128 + ((ks * 64 + lh * 16) ^ rsw));
                    ctx[nt] = __builtin_amdgcn_mfma_f32_16x16x32_bf16(pa, vb, ctx[nt], 0, 0, 0);
                }
            }
            __builtin_amdgcn_s_setprio(0);
            // vectorized attn store: re-read Plds, 4 lanes/row, float4 stores
            #pragma unroll
            for (int j = 0; j < 2; ++j) {
                short8 pv = *(const short8*)&Plds[w][sqr * 64 + ((sm * 16 + j * 8) ^ ((sqr & 7) << 3))];
                float f[8];
                #pragma unroll
                for (int e = 0; e < 8; ++e) f[e] = bf2f((ushort_t)pv[e]);
                float* dst = srowp + c * KB + sm * 16 + j * 8;
                *(float4*)(dst)     = (float4){f[0], f[1], f[2], f[3]};
                *(float4*)(dst + 4) = (float4){f[4], f[5], f[6], f[7]};
            }
        };

        short8 kA = Kt[tid],        vA = Vt8[tid];
        short8 kB = Kt[512 + tid],  vB = Vt8[512 + tid];
        *(short8*)((char*)&Kbuf[0][0] + wphys) = kA;
        *(short8*)((char*)&Vbuf[0][0] + wphys) = vA;
        __syncthreads();
        for (int c = 0; c < nch; c += 2) {
            if (c + 2 < nch) { kA = Kt[(c + 2) * 512 + tid]; vA = Vt8[(c + 2) * 512 + tid]; }
            p2(&Kbuf[0][0], &Vbuf[0][0], c);
            *(short8*)((char*)&Kbuf[1][0] + wphys) = kB;
            *(short8*)((char*)&Vbuf[1][0] + wphys) = vB;
            __syncthreads();
            if (c + 3 < nch) { kB = Kt[(c + 3) * 512 + tid]; vB = Vt8[(c + 3) * 512 + tid]; }
            p2(&Kbuf[1][0], &Vbuf[1][0], c + 1);
            if (c + 2 < nch) {
                *(short8*)((char*)&Kbuf[0][0] + wphys) = kA;
                *(short8*)((char*)&Vbuf[0][0] + wphys) = vA;
            }
            __syncthreads();
        }
    }

    // context epilogue
    #pragma unroll
    for (int nt = 0; nt < 4; ++nt)
        #pragma unroll
        for (int rr = 0; rr < 4; ++rr)
            ctx_out[((size_t)bh * S_LEN + qw + lh * 4 + rr) * D_K + nt * 16 + lr] = ctx[nt][rr];

    // zero-fill fully-masked tail columns
    const int k0 = nch * KB;
    if (k0 < S_LEN) {
        const float4 z = {0.f, 0.f, 0.f, 0.f};
        for (int rr = 0; rr < 128; ++rr) {
            float* rowp = attn_out + ((size_t)bh * S_LEN + q0 + rr) * S_LEN;
            for (int k = k0 + tid * 4; k < S_LEN; k += 512 * 4)
                *(float4*)(rowp + k) = z;
        }
    }
}

// ===================== fallback (round-1 kernel, no ws) =====================
constexpr int LDP = 72;

__global__ __launch_bounds__(256)
void sdpa_fused_v1(const float* __restrict__ Q, const float* __restrict__ K,
                   const float* __restrict__ V, float* __restrict__ out)
{
    __shared__ __align__(16) unsigned short Klds[KB * LDP];
    __shared__ __align__(16) unsigned short Vtlds[D_K * LDP];
    __shared__ __align__(16) unsigned short Pl[4][16 * LDP];

    const int tid = threadIdx.x;
    const int w   = tid >> 6;
    const int l   = tid & 63;
    const int lr  = l & 15;
    const int lh  = l >> 4;

    const int bh   = blockIdx.y;
    const int qblk = (int)gridDim.x - 1 - (int)blockIdx.x;
    const int q0   = qblk * 64;
    const int qw   = q0 + w * 16;
    const int nchunks = qblk + 1;

    const size_t in_base = (size_t)bh * S_LEN * D_K;
    float* ctx_out  = out;
    float* attn_out = out + (size_t)N_BH * S_LEN * D_K;

    short8 qhi[2], qlo[2];
    {
        const float* qrow = Q + in_base + (size_t)(qw + lr) * D_K;
        #pragma unroll
        for (int ds = 0; ds < 2; ++ds) {
            const float4* p4 = (const float4*)(qrow + ds * 32 + lh * 8);
            float4 a = p4[0], b = p4[1];
            float x[8] = {a.x, a.y, a.z, a.w, b.x, b.y, b.z, b.w};
            short8 hi, lo;
            #pragma unroll
            for (int j = 0; j < 8; ++j) {
                unsigned short h = f2bf(x[j]);
                hi[j] = (short)h;
                lo[j] = (short)f2bf(x[j] - bf2f(h));
            }
            qhi[ds] = hi; qlo[ds] = lo;
        }
    }

    const int srow = tid >> 2;
    const int scol = (tid & 3) * 16;
    const float* kstage = K + in_base + (size_t)srow * D_K + scol;
    const float* vstage = V + in_base + (size_t)srow * D_K + scol;

    float inv_[4];
    {
        float sum[4] = {0.f, 0.f, 0.f, 0.f};
        for (int c = 0; c < nchunks; ++c) {
            {
                const float4* kp = (const float4*)(kstage + (size_t)c * KB * D_K);
                float4 a0 = kp[0], a1 = kp[1], a2 = kp[2], a3 = kp[3];
                float x[16] = {a0.x,a0.y,a0.z,a0.w, a1.x,a1.y,a1.z,a1.w,
                               a2.x,a2.y,a2.z,a2.w, a3.x,a3.y,a3.z,a3.w};
                short8 w0, w1;
                #pragma unroll
                for (int j = 0; j < 8; ++j) {
                    w0[j] = (short)f2bf(x[j]     * 0.125f);
                    w1[j] = (short)f2bf(x[j + 8] * 0.125f);
                }
                *(short8*)&Klds[srow * LDP + scol]     = w0;
                *(short8*)&Klds[srow * LDP + scol + 8] = w1;
            }
            __syncthreads();
            #pragma unroll
            for (int nt = 0; nt < 4; ++nt) {
                f32x4 acc = {0.f, 0.f, 0.f, 0.f};
                #pragma unroll
                for (int ks = 0; ks < 2; ++ks) {
                    short8 bk = *(const short8*)&Klds[(nt*16 + lr) * LDP + ks*32 + lh*8];
                    acc = __builtin_amdgcn_mfma_f32_16x16x32_bf16(qhi[ks], bk, acc, 0, 0, 0);
                    acc = __builtin_amdgcn_mfma_f32_16x16x32_bf16(qlo[ks], bk, acc, 0, 0, 0);
                }
                const int kg = c * KB + nt * 16 + lr;
                #pragma unroll
                for (int rr = 0; rr < 4; ++rr) {
                    if (kg <= qw + lh * 4 + rr)
                        sum[rr] += __expf(fminf(acc[rr], 60.f));
                }
            }
            __syncthreads();
        }
        #pragma unroll
        for (int rr = 0; rr < 4; ++rr) {
            float t = sum[rr];
            t += __shfl_xor(t, 1);
            t += __shfl_xor(t, 2);
            t += __shfl_xor(t, 4);
            t += __shfl_xor(t, 8);
            inv_[rr] = 1.f / t;
        }
    }

    f32x4 ctx[4];
    #pragma unroll
    for (int nt = 0; nt < 4; ++nt) ctx[nt] = (f32x4){0.f, 0.f, 0.f, 0.f};

    for (int c = 0; c < nchunks; ++c) {
        {
            const float4* kp = (const float4*)(kstage + (size_t)c * KB * D_K);
            float4 a0 = kp[0], a1 = kp[1], a2 = kp[2], a3 = kp[3];
            float x[16] = {a0.x,a0.y,a0.z,a0.w, a1.x,a1.y,a1.z,a1.w,
                           a2.x,a2.y,a2.z,a2.w, a3.x,a3.y,a3.z,a3.w};
            short8 w0, w1;
            #pragma unroll
            for (int j = 0; j < 8; ++j) {
                w0[j] = (short)f2bf(x[j]     * 0.125f);
                w1[j] = (short)f2bf(x[j + 8] * 0.125f);
            }
            *(short8*)&Klds[srow * LDP + scol]     = w0;
            *(short8*)&Klds[srow * LDP + scol + 8] = w1;

            const float4* vp = (const float4*)(vstage + (size_t)c * KB * D_K);
            float4 b0 = vp[0], b1 = vp[1], b2 = vp[2], b3 = vp[3];
            float y[16] = {b0.x,b0.y,b0.z,b0.w, b1.x,b1.y,b1.z,b1.w,
                           b2.x,b2.y,b2.z,b2.w, b3.x,b3.y,b3.z,b3.w};
            #pragma unroll
            for (int j = 0; j < 16; ++j)
                Vtlds[(scol + j) * LDP + srow] = f2bf(y[j]);
        }
        __syncthreads();

        #pragma unroll
        for (int nt = 0; nt < 4; ++nt) {
            f32x4 acc = {0.f, 0.f, 0.f, 0.f};
            #pragma unroll
            for (int ks = 0; ks < 2; ++ks) {
                short8 bk = *(const short8*)&Klds[(nt*16 + lr) * LDP + ks*32 + lh*8];
                acc = __builtin_amdgcn_mfma_f32_16x16x32_bf16(qhi[ks], bk, acc, 0, 0, 0);
                acc = __builtin_amdgcn_mfma_f32_16x16x32_bf16(qlo[ks], bk, acc, 0, 0, 0);
            }
            const int kg = c * KB + nt * 16 + lr;
            #pragma unroll
            for (int rr = 0; rr < 4; ++rr) {
                const int qg = qw + lh * 4 + rr;
                float p = (kg <= qg) ? __expf(fminf(acc[rr], 60.f)) * inv_[rr] : 0.f;
                attn_out[((size_t)bh * S_LEN + qg) * S_LEN + kg] = p;
                Pl[w][(lh * 4 + rr) * LDP + nt * 16 + lr] = f2bf(p);
            }
        }
        __syncthreads();

        #pragma unroll
        for (int ks = 0; ks < 2; ++ks) {
            short8 pa = *(const short8*)&Pl[w][lr * LDP + ks*32 + lh*8];
            #pragma unroll
            for (int nt = 0; nt < 4; ++nt) {
                short8 vb = *(const short8*)&Vtlds[(nt*16 + lr) * LDP + ks*32 + lh*8];
                ctx[nt] = __builtin_amdgcn_mfma_f32_16x16x32_bf16(pa, vb, ctx[nt], 0, 0, 0);
            }
        }
        __syncthreads();
    }

    #pragma unroll
    for (int nt = 0; nt < 4; ++nt)
        #pragma unroll
        for (int rr = 0; rr < 4; ++rr)
            ctx_out[((size_t)bh * S_LEN + qw + lh * 4 + rr) * D_K + nt * 16 + lr] = ctx[nt][rr];

    const int k0 = nchunks * KB;
    if (k0 < S_LEN) {
        const float4 z = {0.f, 0.f, 0.f, 0.f};
        for (int rr = 0; rr < 64; ++rr) {
            float* rowp = attn_out + ((size_t)bh * S_LEN + q0 + rr) * S_LEN;
            for (int k = k0 + tid * 4; k < S_LEN; k += 256 * 4)
                *(float4*)(rowp + k) = z;
        }
    }
}

extern "C" void kernel_launch(void* const* d_in, const int* in_sizes, int n_in,
                              void* d_out, int out_size, void* d_ws, size_t ws_size,
                              hipStream_t stream)
{
    const float* Q = (const float*)d_in[0];
    const float* K = (const float*)d_in[1];
    const float* V = (const float*)d_in[2];
    float* out = (float*)d_out;

    const size_t ws_needed = (size_t)2 * N_BH * S_LEN * D_K * sizeof(ushort_t);  // 16.8 MB
    if (ws_size >= ws_needed) {
        ushort_t* Kws = (ushort_t*)d_ws;
        ushort_t* Vws = Kws + (size_t)N_BH * S_LEN * D_K;
        prep_k<<<2048, 256, 0, stream>>>(K, Kws);
        prep_v<<<2048, 256, 0, stream>>>(V, Vws);
        sdpa_main<<<512, 512, 0, stream>>>(Q, Kws, Vws, out);
    } else {
        dim3 grid(S_LEN / 64, N_BH);
        sdpa_fused_v1<<<grid, 256, 0, stream>>>(Q, K, V, out);
    }
}

// Round 4
// 188.119 us; speedup vs baseline: 1.1397x; 1.1397x over previous
//
#include <hip/hip_runtime.h>

constexpr int S_LEN = 2048;
constexpr int D_K   = 64;
constexpr int N_BH  = 32;   // B*H
constexpr int KB    = 64;   // k per chunk

typedef __attribute__((ext_vector_type(8))) short short8;
typedef __attribute__((ext_vector_type(4))) float f32x4;
typedef unsigned short ushort_t;

__device__ __forceinline__ unsigned short f2bf(float f) {
    unsigned int u = __builtin_bit_cast(unsigned int, f);
    u += 0x7fffu + ((u >> 16) & 1u);          // round-to-nearest-even
    return (unsigned short)(u >> 16);
}
__device__ __forceinline__ float bf2f(unsigned short h) {
    unsigned int u = ((unsigned int)h) << 16;
    return __builtin_bit_cast(float, u);
}

// ============================ prep kernels ============================
__global__ __launch_bounds__(256)
void prep_k(const float* __restrict__ K, ushort_t* __restrict__ Kws) {
    const int idx = blockIdx.x * 256 + threadIdx.x;
    const float4* src = (const float4*)K + (size_t)idx * 2;
    float4 a = src[0], b = src[1];
    float x[8] = {a.x, a.y, a.z, a.w, b.x, b.y, b.z, b.w};
    short8 o;
    #pragma unroll
    for (int j = 0; j < 8; ++j) o[j] = (short)f2bf(x[j] * 0.125f);
    *(short8*)(Kws + (size_t)idx * 8) = o;
}

__global__ __launch_bounds__(256)
void prep_v(const float* __restrict__ V, ushort_t* __restrict__ Vws) {
    const int gid = blockIdx.x * 256 + threadIdx.x;
    const int u   = gid & 511;
    const int bc  = gid >> 9;
    const int c   = bc & 31;
    const int bh  = bc >> 5;
    const int kg  = u >> 6;
    const int d   = u & 63;
    const float* vp = V + ((size_t)bh * S_LEN + c * KB + kg * 8) * D_K + d;
    short8 o;
    #pragma unroll
    for (int i = 0; i < 8; ++i) o[i] = (short)f2bf(vp[(size_t)i * D_K]);
    *(short8*)(Vws + ((size_t)(bh * 32 + c) * D_K + d) * KB + kg * 8) = o;
}

// ============================ main kernel =============================
// 512 blocks x 512 threads. Every block IDENTICAL work: processes q-tiles
// t = 31-r and t = r (64 rows each) of head bh; total chunks = 33 per block.
// 8 waves split a tile: g = w&3 row-group (16 rows), h2 = w>>2 k/d-half.
// K/V LDS tiles [64][64] bf16, XOR-swizzled: byte = row*128 + (col ^ ((row&7)<<4)).
__global__ __launch_bounds__(512, 4)
void sdpa_main(const float* __restrict__ Q, const ushort_t* __restrict__ Kws,
               const ushort_t* __restrict__ Vws, float* __restrict__ out)
{
    __shared__ __align__(16) ushort_t Kbuf[2][4096];
    __shared__ __align__(16) ushort_t Vbuf[2][4096];
    __shared__ __align__(16) ushort_t Plds[8][1024];   // region [g + 4*khalf]: 16 rows x 64 cols
    __shared__ float sred[2][4][16];

    const int tid = threadIdx.x;
    const int w   = tid >> 6;
    const int l   = tid & 63;
    const int lr  = l & 15;
    const int lh  = l >> 4;
    const int g   = w & 3;        // row group (16 q rows)
    const int h2  = w >> 2;       // k-half (QK) / d-half (PV)

    const int bx = blockIdx.x;    // 0..511
    const int bh = bx >> 4;
    const int r  = bx & 15;

    float* ctx_out  = out;                                   // [BH][S][D]
    float* attn_out = out + (size_t)N_BH * S_LEN * D_K;      // [BH][S][S]

    const short8* Kt  = (const short8*)(Kws + (size_t)bh * S_LEN * D_K);   // chunk c at c*512
    const short8* Vt8 = (const short8*)(Vws + (size_t)bh * 32 * 4096);

    const int wrow  = tid >> 3;
    const int wcol  = (tid & 7) << 4;
    const int wphys = wrow * 128 + (wcol ^ ((wrow & 7) << 4));
    const int rsw   = (lr & 7) << 4;     // K/V frag-read swizzle (bytes)

    auto run_tile = [&](int qt0, int nch) {
        // ---- Q fragments for rows qt0 + g*16 + lr, hi/lo bf16 split ----
        short8 qhi[2], qlo[2];
        {
            const float* qrow = Q + ((size_t)bh * S_LEN + qt0 + g * 16 + lr) * D_K;
            #pragma unroll
            for (int ds = 0; ds < 2; ++ds) {
                const float4* p4 = (const float4*)(qrow + ds * 32 + lh * 8);
                float4 a = p4[0], bq = p4[1];
                float x[8] = {a.x, a.y, a.z, a.w, bq.x, bq.y, bq.z, bq.w};
                short8 hi, lo;
                #pragma unroll
                for (int j = 0; j < 8; ++j) {
                    unsigned short h = f2bf(x[j]);
                    hi[j] = (short)h;
                    lo[j] = (short)f2bf(x[j] - bf2f(h));
                }
                qhi[ds] = hi; qlo[ds] = lo;
            }
        }
        const int qg_base = qt0 + g * 16 + lh * 4;   // + rr = this lane's q rows

        // ================= PASS 1: row sums (k-half per wave) =================
        float inv_[4];
        {
            float sum[4] = {0.f, 0.f, 0.f, 0.f};
            short8 kst = Kt[tid];
            *(short8*)((char*)&Kbuf[0][0] + wphys) = kst;
            __syncthreads();
            for (int c = 0; c < nch; ++c) {
                if (c + 1 < nch) kst = Kt[(c + 1) * 512 + tid];
                const char* Kb = (const char*)&Kbuf[c & 1][0];
                #pragma unroll
                for (int nt2 = 0; nt2 < 2; ++nt2) {
                    const int ntg = h2 * 2 + nt2;
                    f32x4 acc = {0.f, 0.f, 0.f, 0.f};
                    #pragma unroll
                    for (int ks = 0; ks < 2; ++ks) {
                        short8 bk = *(const short8*)(Kb + (ntg * 16 + lr) * 128 + ((ks * 64 + lh * 16) ^ rsw));
                        acc = __builtin_amdgcn_mfma_f32_16x16x32_bf16(qhi[ks], bk, acc, 0, 0, 0);
                        acc = __builtin_amdgcn_mfma_f32_16x16x32_bf16(qlo[ks], bk, acc, 0, 0, 0);
                    }
                    const int kg = c * KB + ntg * 16 + lr;
                    #pragma unroll
                    for (int rr = 0; rr < 4; ++rr) {
                        if (kg <= qg_base + rr)
                            sum[rr] += __expf(fminf(acc[rr], 60.f));
                    }
                }
                if (c + 1 < nch) *(short8*)((char*)&Kbuf[(c + 1) & 1][0] + wphys) = kst;
                __syncthreads();
            }
            #pragma unroll
            for (int rr = 0; rr < 4; ++rr) {   // butterfly over the 16 col-lanes
                float t = sum[rr];
                t += __shfl_xor(t, 1);
                t += __shfl_xor(t, 2);
                t += __shfl_xor(t, 4);
                t += __shfl_xor(t, 8);
                sum[rr] = t;
            }
            if (lr == 0) {
                #pragma unroll
                for (int rr = 0; rr < 4; ++rr) sred[h2][g][lh * 4 + rr] = sum[rr];
            }
            __syncthreads();
            #pragma unroll
            for (int rr = 0; rr < 4; ++rr)
                inv_[rr] = 1.f / (sred[0][g][lh * 4 + rr] + sred[1][g][lh * 4 + rr]);
            __syncthreads();   // sred safe for next tile; Kbuf reuse below re-synced anyway
        }

        // ================= PASS 2: attn write + PV =================
        f32x4 ctx[2];
        ctx[0] = (f32x4){0.f, 0.f, 0.f, 0.f};
        ctx[1] = (f32x4){0.f, 0.f, 0.f, 0.f};

        {
            short8 kst = Kt[tid], vst = Vt8[tid];
            *(short8*)((char*)&Kbuf[0][0] + wphys) = kst;
            *(short8*)((char*)&Vbuf[0][0] + wphys) = vst;
            __syncthreads();
            for (int c = 0; c < nch; ++c) {
                if (c + 1 < nch) { kst = Kt[(c + 1) * 512 + tid]; vst = Vt8[(c + 1) * 512 + tid]; }
                const char* Kb = (const char*)&Kbuf[c & 1][0];
                const char* Vb = (const char*)&Vbuf[c & 1][0];

                // QK^T (this wave's k-half), write normalized attn f32, stage P bf16
                #pragma unroll
                for (int nt2 = 0; nt2 < 2; ++nt2) {
                    const int ntg = h2 * 2 + nt2;
                    f32x4 acc = {0.f, 0.f, 0.f, 0.f};
                    #pragma unroll
                    for (int ks = 0; ks < 2; ++ks) {
                        short8 bk = *(const short8*)(Kb + (ntg * 16 + lr) * 128 + ((ks * 64 + lh * 16) ^ rsw));
                        acc = __builtin_amdgcn_mfma_f32_16x16x32_bf16(qhi[ks], bk, acc, 0, 0, 0);
                        acc = __builtin_amdgcn_mfma_f32_16x16x32_bf16(qlo[ks], bk, acc, 0, 0, 0);
                    }
                    const int kg = c * KB + ntg * 16 + lr;
                    #pragma unroll
                    for (int rr = 0; rr < 4; ++rr) {
                        const int pwr = lh * 4 + rr;
                        const int qg  = qg_base + rr;
                        float p = (kg <= qg) ? __expf(fminf(acc[rr], 60.f)) * inv_[rr] : 0.f;
                        attn_out[((size_t)bh * S_LEN + qg) * S_LEN + kg] = p;
                        Plds[g + 4 * h2][pwr * 64 + ((ntg * 16 + lr) ^ ((pwr & 7) << 3))] = f2bf(p);
                    }
                }
                __syncthreads();   // P visible across wave pairs

                // PV: this wave's d-half (ntg), both k-halves via partner Plds regions
                #pragma unroll
                for (int ks = 0; ks < 2; ++ks) {
                    short8 pa = *(const short8*)&Plds[g + 4 * ks][lr * 64 + ((ks * 32 + lh * 8) ^ ((lr & 7) << 3))];
                    #pragma unroll
                    for (int nt2 = 0; nt2 < 2; ++nt2) {
                        const int ntg = h2 * 2 + nt2;
                        short8 vb = *(const short8*)(Vb + (ntg * 16 + lr) * 128 + ((ks * 64 + lh * 16) ^ rsw));
                        ctx[nt2] = __builtin_amdgcn_mfma_f32_16x16x32_bf16(pa, vb, ctx[nt2], 0, 0, 0);
                    }
                }

                if (c + 1 < nch) {
                    *(short8*)((char*)&Kbuf[(c + 1) & 1][0] + wphys) = kst;
                    *(short8*)((char*)&Vbuf[(c + 1) & 1][0] + wphys) = vst;
                }
                __syncthreads();
            }
        }

        // context stores: rows qg_base+rr, cols ntg*16+lr (this wave's d-half)
        #pragma unroll
        for (int nt2 = 0; nt2 < 2; ++nt2) {
            const int ntg = h2 * 2 + nt2;
            #pragma unroll
            for (int rr = 0; rr < 4; ++rr)
                ctx_out[((size_t)bh * S_LEN + qg_base + rr) * D_K + ntg * 16 + lr] = ctx[nt2][rr];
        }

        // zero-fill fully-masked tail columns of this tile (64 rows, 8 threads/row)
        const int k0 = nch * KB;
        if (k0 < S_LEN) {
            const float4 z = {0.f, 0.f, 0.f, 0.f};
            float* rowp = attn_out + ((size_t)bh * S_LEN + qt0 + (tid >> 3)) * S_LEN;
            for (int k = k0 + (tid & 7) * 4; k < S_LEN; k += 32)
                *(float4*)(rowp + k) = z;
        }
    };

    // long tile first, then short; every block does exactly 33 chunk-units/pass
    run_tile((31 - r) * 64, 32 - r);
    run_tile(r * 64, r + 1);
}

// ===================== fallback (round-1 kernel, no ws) =====================
constexpr int LDP = 72;

__global__ __launch_bounds__(256)
void sdpa_fused_v1(const float* __restrict__ Q, const float* __restrict__ K,
                   const float* __restrict__ V, float* __restrict__ out)
{
    __shared__ __align__(16) unsigned short Klds[KB * LDP];
    __shared__ __align__(16) unsigned short Vtlds[D_K * LDP];
    __shared__ __align__(16) unsigned short Pl[4][16 * LDP];

    const int tid = threadIdx.x;
    const int w   = tid >> 6;
    const int l   = tid & 63;
    const int lr  = l & 15;
    const int lh  = l >> 4;

    const int bh   = blockIdx.y;
    const int qblk = (int)gridDim.x - 1 - (int)blockIdx.x;
    const int q0   = qblk * 64;
    const int qw   = q0 + w * 16;
    const int nchunks = qblk + 1;

    const size_t in_base = (size_t)bh * S_LEN * D_K;
    float* ctx_out  = out;
    float* attn_out = out + (size_t)N_BH * S_LEN * D_K;

    short8 qhi[2], qlo[2];
    {
        const float* qrow = Q + in_base + (size_t)(qw + lr) * D_K;
        #pragma unroll
        for (int ds = 0; ds < 2; ++ds) {
            const float4* p4 = (const float4*)(qrow + ds * 32 + lh * 8);
            float4 a = p4[0], b = p4[1];
            float x[8] = {a.x, a.y, a.z, a.w, b.x, b.y, b.z, b.w};
            short8 hi, lo;
            #pragma unroll
            for (int j = 0; j < 8; ++j) {
                unsigned short h = f2bf(x[j]);
                hi[j] = (short)h;
                lo[j] = (short)f2bf(x[j] - bf2f(h));
            }
            qhi[ds] = hi; qlo[ds] = lo;
        }
    }

    const int srow = tid >> 2;
    const int scol = (tid & 3) * 16;
    const float* kstage = K + in_base + (size_t)srow * D_K + scol;
    const float* vstage = V + in_base + (size_t)srow * D_K + scol;

    float inv_[4];
    {
        float sum[4] = {0.f, 0.f, 0.f, 0.f};
        for (int c = 0; c < nchunks; ++c) {
            {
                const float4* kp = (const float4*)(kstage + (size_t)c * KB * D_K);
                float4 a0 = kp[0], a1 = kp[1], a2 = kp[2], a3 = kp[3];
                float x[16] = {a0.x,a0.y,a0.z,a0.w, a1.x,a1.y,a1.z,a1.w,
                               a2.x,a2.y,a2.z,a2.w, a3.x,a3.y,a3.z,a3.w};
                short8 w0, w1;
                #pragma unroll
                for (int j = 0; j < 8; ++j) {
                    w0[j] = (short)f2bf(x[j]     * 0.125f);
                    w1[j] = (short)f2bf(x[j + 8] * 0.125f);
                }
                *(short8*)&Klds[srow * LDP + scol]     = w0;
                *(short8*)&Klds[srow * LDP + scol + 8] = w1;
            }
            __syncthreads();
            #pragma unroll
            for (int nt = 0; nt < 4; ++nt) {
                f32x4 acc = {0.f, 0.f, 0.f, 0.f};
                #pragma unroll
                for (int ks = 0; ks < 2; ++ks) {
                    short8 bk = *(const short8*)&Klds[(nt*16 + lr) * LDP + ks*32 + lh*8];
                    acc = __builtin_amdgcn_mfma_f32_16x16x32_bf16(qhi[ks], bk, acc, 0, 0, 0);
                    acc = __builtin_amdgcn_mfma_f32_16x16x32_bf16(qlo[ks], bk, acc, 0, 0, 0);
                }
                const int kg = c * KB + nt * 16 + lr;
                #pragma unroll
                for (int rr = 0; rr < 4; ++rr) {
                    if (kg <= qw + lh * 4 + rr)
                        sum[rr] += __expf(fminf(acc[rr], 60.f));
                }
            }
            __syncthreads();
        }
        #pragma unroll
        for (int rr = 0; rr < 4; ++rr) {
            float t = sum[rr];
            t += __shfl_xor(t, 1);
            t += __shfl_xor(t, 2);
            t += __shfl_xor(t, 4);
            t += __shfl_xor(t, 8);
            inv_[rr] = 1.f / t;
        }
    }

    f32x4 ctx[4];
    #pragma unroll
    for (int nt = 0; nt < 4; ++nt) ctx[nt] = (f32x4){0.f, 0.f, 0.f, 0.f};

    for (int c = 0; c < nchunks; ++c) {
        {
            const float4* kp = (const float4*)(kstage + (size_t)c * KB * D_K);
            float4 a0 = kp[0], a1 = kp[1], a2 = kp[2], a3 = kp[3];
            float x[16] = {a0.x,a0.y,a0.z,a0.w, a1.x,a1.y,a1.z,a1.w,
                           a2.x,a2.y,a2.z,a2.w, a3.x,a3.y,a3.z,a3.w};
            short8 w0, w1;
            #pragma unroll
            for (int j = 0; j < 8; ++j) {
                w0[j] = (short)f2bf(x[j]     * 0.125f);
                w1[j] = (short)f2bf(x[j + 8] * 0.125f);
            }
            *(short8*)&Klds[srow * LDP + scol]     = w0;
            *(short8*)&Klds[srow * LDP + scol + 8] = w1;

            const float4* vp = (const float4*)(vstage + (size_t)c * KB * D_K);
            float4 b0 = vp[0], b1 = vp[1], b2 = vp[2], b3 = vp[3];
            float y[16] = {b0.x,b0.y,b0.z,b0.w, b1.x,b1.y,b1.z,b1.w,
                           b2.x,b2.y,b2.z,b2.w, b3.x,b3.y,b3.z,b3.w};
            #pragma unroll
            for (int j = 0; j < 16; ++j)
                Vtlds[(scol + j) * LDP + srow] = f2bf(y[j]);
        }
        __syncthreads();

        #pragma unroll
        for (int nt = 0; nt < 4; ++nt) {
            f32x4 acc = {0.f, 0.f, 0.f, 0.f};
            #pragma unroll
            for (int ks = 0; ks < 2; ++ks) {
                short8 bk = *(const short8*)&Klds[(nt*16 + lr) * LDP + ks*32 + lh*8];
                acc = __builtin_amdgcn_mfma_f32_16x16x32_bf16(qhi[ks], bk, acc, 0, 0, 0);
                acc = __builtin_amdgcn_mfma_f32_16x16x32_bf16(qlo[ks], bk, acc, 0, 0, 0);
            }
            const int kg = c * KB + nt * 16 + lr;
            #pragma unroll
            for (int rr = 0; rr < 4; ++rr) {
                const int qg = qw + lh * 4 + rr;
                float p = (kg <= qg) ? __expf(fminf(acc[rr], 60.f)) * inv_[rr] : 0.f;
                attn_out[((size_t)bh * S_LEN + qg) * S_LEN + kg] = p;
                Pl[w][(lh * 4 + rr) * LDP + nt * 16 + lr] = f2bf(p);
            }
        }
        __syncthreads();

        #pragma unroll
        for (int ks = 0; ks < 2; ++ks) {
            short8 pa = *(const short8*)&Pl[w][lr * LDP + ks*32 + lh*8];
            #pragma unroll
            for (int nt = 0; nt < 4; ++nt) {
                short8 vb = *(const short8*)&Vtlds[(nt*16 + lr) * LDP + ks*32 + lh*8];
                ctx[nt] = __builtin_amdgcn_mfma_f32_16x16x32_bf16(pa, vb, ctx[nt], 0, 0, 0);
            }
        }
        __syncthreads();
    }

    #pragma unroll
    for (int nt = 0; nt < 4; ++nt)
        #pragma unroll
        for (int rr = 0; rr < 4; ++rr)
            ctx_out[((size_t)bh * S_LEN + qw + lh * 4 + rr) * D_K + nt * 16 + lr] = ctx[nt][rr];

    const int k0 = nchunks * KB;
    if (k0 < S_LEN) {
        const float4 z = {0.f, 0.f, 0.f, 0.f};
        for (int rr = 0; rr < 64; ++rr) {
            float* rowp = attn_out + ((size_t)bh * S_LEN + q0 + rr) * S_LEN;
            for (int k = k0 + tid * 4; k < S_LEN; k += 256 * 4)
                *(float4*)(rowp + k) = z;
        }
    }
}

extern "C" void kernel_launch(void* const* d_in, const int* in_sizes, int n_in,
                              void* d_out, int out_size, void* d_ws, size_t ws_size,
                              hipStream_t stream)
{
    const float* Q = (const float*)d_in[0];
    const float* K = (const float*)d_in[1];
    const float* V = (const float*)d_in[2];
    float* out = (float*)d_out;

    const size_t ws_needed = (size_t)2 * N_BH * S_LEN * D_K * sizeof(ushort_t);  // 16.8 MB
    if (ws_size >= ws_needed) {
        ushort_t* Kws = (ushort_t*)d_ws;
        ushort_t* Vws = Kws + (size_t)N_BH * S_LEN * D_K;
        prep_k<<<2048, 256, 0, stream>>>(K, Kws);
        prep_v<<<2048, 256, 0, stream>>>(V, Vws);
        sdpa_main<<<512, 512, 0, stream>>>(Q, Kws, Vws, out);
    } else {
        dim3 grid(S_LEN / 64, N_BH);
        sdpa_fused_v1<<<grid, 256, 0, stream>>>(Q, K, V, out);
    }
}

// Round 5
// 182.347 us; speedup vs baseline: 1.1757x; 1.0317x over previous
//
#include <hip/hip_runtime.h>

constexpr int S_LEN = 2048;
constexpr int D_K   = 64;
constexpr int N_BH  = 32;   // B*H
constexpr int KB    = 64;   // k per chunk

typedef __attribute__((ext_vector_type(8))) short short8;
typedef __attribute__((ext_vector_type(4))) float f32x4;
typedef unsigned short ushort_t;

__device__ __forceinline__ unsigned short f2bf(float f) {
    unsigned int u = __builtin_bit_cast(unsigned int, f);
    u += 0x7fffu + ((u >> 16) & 1u);          // round-to-nearest-even
    return (unsigned short)(u >> 16);
}
__device__ __forceinline__ float bf2f(unsigned short h) {
    unsigned int u = ((unsigned int)h) << 16;
    return __builtin_bit_cast(float, u);
}

// ============================ prep kernels ============================
__global__ __launch_bounds__(256)
void prep_k(const float* __restrict__ K, ushort_t* __restrict__ Kws) {
    const int idx = blockIdx.x * 256 + threadIdx.x;
    const float4* src = (const float4*)K + (size_t)idx * 2;
    float4 a = src[0], b = src[1];
    float x[8] = {a.x, a.y, a.z, a.w, b.x, b.y, b.z, b.w};
    short8 o;
    #pragma unroll
    for (int j = 0; j < 8; ++j) o[j] = (short)f2bf(x[j] * 0.125f);
    *(short8*)(Kws + (size_t)idx * 8) = o;
}

__global__ __launch_bounds__(256)
void prep_v(const float* __restrict__ V, ushort_t* __restrict__ Vws) {
    const int gid = blockIdx.x * 256 + threadIdx.x;
    const int u   = gid & 511;
    const int bc  = gid >> 9;
    const int c   = bc & 31;
    const int bh  = bc >> 5;
    const int kg  = u >> 6;
    const int d   = u & 63;
    const float* vp = V + ((size_t)bh * S_LEN + c * KB + kg * 8) * D_K + d;
    short8 o;
    #pragma unroll
    for (int i = 0; i < 8; ++i) o[i] = (short)f2bf(vp[(size_t)i * D_K]);
    *(short8*)(Vws + ((size_t)(bh * 32 + c) * D_K + d) * KB + kg * 8) = o;
}

// ============================ main kernel =============================
// 512 blocks x 512 threads. Block handles TWO 64-row q-tiles CONCURRENTLY:
// waves 0-3 -> tile 31-r (nchA = 32-r chunks), waves 4-7 -> tile r (nchB = r+1).
// One chunk loop of length nchA serves both tiles from shared staged K/V.
// Each wave: 16 q rows, full-width QK (16 MFMA), private Plds, full PV (8 MFMA).
// ONE barrier per chunk; distance-2 prefetch via even/odd named regs.
// Block mapping: b and b+256 get complementary r -> per-CU total = 98 iters, equal.
__global__ __launch_bounds__(512, 4)
void sdpa_main(const float* __restrict__ Q, const ushort_t* __restrict__ Kws,
               const ushort_t* __restrict__ Vws, float* __restrict__ out)
{
    __shared__ __align__(16) ushort_t Kbuf[2][4096];
    __shared__ __align__(16) ushort_t Vbuf[2][4096];
    __shared__ __align__(16) ushort_t Plds[8][1024];   // per-wave 16 rows x 64 cols

    const int tid  = threadIdx.x;
    const int w    = tid >> 6;
    const int l    = tid & 63;
    const int lr   = l & 15;
    const int lh   = l >> 4;
    const int g    = w & 3;        // row group within my tile
    const int half = w >> 2;       // 0: long tile, 1: short tile

    const int b  = blockIdx.x;     // 0..511
    const int s  = b >> 8;
    const int i  = b & 255;
    const int bh = (i >> 4) + s * 16;
    const int r0 = i & 15;
    const int r  = s ? (15 - r0) : r0;   // complementary pairing across b / b+256

    const int nchA  = 32 - r;            // >= 17
    const int nchB  = r + 1;             // <= 16 < nchA
    const int q0    = (half ? r : (31 - r)) * 64;
    const int mynch = half ? nchB : nchA;
    const int qg_base = q0 + g * 16 + lh * 4;    // + rr = this lane's q rows

    float* ctx_out  = out;                                   // [BH][S][D]
    float* attn_out = out + (size_t)N_BH * S_LEN * D_K;      // [BH][S][S]

    const short8* Kt  = (const short8*)(Kws + (size_t)bh * S_LEN * D_K);   // chunk c at c*512
    const short8* Vt8 = (const short8*)(Vws + (size_t)bh * 32 * 4096);

    const int wrow  = tid >> 3;
    const int wcol  = (tid & 7) << 4;
    const int wphys = wrow * 128 + (wcol ^ ((wrow & 7) << 4));  // swizzled LDS write pos
    const int rsw   = (lr & 7) << 4;                            // K/V frag-read swizzle

    // ---- Q fragments for my 16 rows, hi/lo bf16 split ----
    short8 qhi[2], qlo[2];
    {
        const float* qrow = Q + ((size_t)bh * S_LEN + q0 + g * 16 + lr) * D_K;
        #pragma unroll
        for (int ds = 0; ds < 2; ++ds) {
            const float4* p4 = (const float4*)(qrow + ds * 32 + lh * 8);
            float4 a = p4[0], bq = p4[1];
            float x[8] = {a.x, a.y, a.z, a.w, bq.x, bq.y, bq.z, bq.w};
            short8 hi, lo;
            #pragma unroll
            for (int j = 0; j < 8; ++j) {
                unsigned short h = f2bf(x[j]);
                hi[j] = (short)h;
                lo[j] = (short)f2bf(x[j] - bf2f(h));
            }
            qhi[ds] = hi; qlo[ds] = lo;
        }
    }

    // ================= PASS 1: row sums =================
    float inv_[4];
    {
        float sum[4] = {0.f, 0.f, 0.f, 0.f};

        auto qk_sum = [&](const char* Kb, int c) {
            #pragma unroll
            for (int nt = 0; nt < 4; ++nt) {
                f32x4 acc = {0.f, 0.f, 0.f, 0.f};
                #pragma unroll
                for (int ks = 0; ks < 2; ++ks) {
                    short8 bk = *(const short8*)(Kb + (nt * 16 + lr) * 128 + ((ks * 64 + lh * 16) ^ rsw));
                    acc = __builtin_amdgcn_mfma_f32_16x16x32_bf16(qhi[ks], bk, acc, 0, 0, 0);
                    acc = __builtin_amdgcn_mfma_f32_16x16x32_bf16(qlo[ks], bk, acc, 0, 0, 0);
                }
                const int kg = c * KB + nt * 16 + lr;
                #pragma unroll
                for (int rr = 0; rr < 4; ++rr)
                    if (kg <= qg_base + rr) sum[rr] += __expf(fminf(acc[rr], 60.f));
            }
        };

        short8 kE = Kt[tid];                                   // chunk 0
        *(short8*)((char*)&Kbuf[0][0] + wphys) = kE;
        short8 kO = Kt[512 + tid];                             // chunk 1 (nchA >= 17)
        __syncthreads();
        for (int c = 0; c < nchA; c += 2) {
            if (c + 2 < nchA) kE = Kt[(c + 2) * 512 + tid];    // dist-2 prefetch
            if (c < mynch) qk_sum((const char*)&Kbuf[0][0], c);
            if (c + 1 < nchA) *(short8*)((char*)&Kbuf[1][0] + wphys) = kO;
            __syncthreads();
            if (c + 1 < nchA) {
                if (c + 3 < nchA) kO = Kt[(c + 3) * 512 + tid];
                if (c + 1 < mynch) qk_sum((const char*)&Kbuf[1][0], c + 1);
                if (c + 2 < nchA) *(short8*)((char*)&Kbuf[0][0] + wphys) = kE;
                __syncthreads();
            }
        }
        #pragma unroll
        for (int rr = 0; rr < 4; ++rr) {   // butterfly over the 16 col-lanes
            float t = sum[rr];
            t += __shfl_xor(t, 1);
            t += __shfl_xor(t, 2);
            t += __shfl_xor(t, 4);
            t += __shfl_xor(t, 8);
            inv_[rr] = 1.f / t;
        }
    }

    // ================= PASS 2: attn write + PV =================
    f32x4 ctx[4];
    #pragma unroll
    for (int nt = 0; nt < 4; ++nt) ctx[nt] = (f32x4){0.f, 0.f, 0.f, 0.f};

    {
        auto p2 = [&](const char* Kb, const char* Vb, int c) {
            // QK^T + exp + write normalized attn f32 + stage P bf16 (private)
            #pragma unroll
            for (int nt = 0; nt < 4; ++nt) {
                f32x4 acc = {0.f, 0.f, 0.f, 0.f};
                #pragma unroll
                for (int ks = 0; ks < 2; ++ks) {
                    short8 bk = *(const short8*)(Kb + (nt * 16 + lr) * 128 + ((ks * 64 + lh * 16) ^ rsw));
                    acc = __builtin_amdgcn_mfma_f32_16x16x32_bf16(qhi[ks], bk, acc, 0, 0, 0);
                    acc = __builtin_amdgcn_mfma_f32_16x16x32_bf16(qlo[ks], bk, acc, 0, 0, 0);
                }
                const int kg = c * KB + nt * 16 + lr;
                #pragma unroll
                for (int rr = 0; rr < 4; ++rr) {
                    const int pwr = lh * 4 + rr;
                    const int qg  = qg_base + rr;
                    float p = (kg <= qg) ? __expf(fminf(acc[rr], 60.f)) * inv_[rr] : 0.f;
                    attn_out[((size_t)bh * S_LEN + qg) * S_LEN + kg] = p;
                    Plds[w][pwr * 64 + ((nt * 16 + lr) ^ ((pwr & 7) << 3))] = f2bf(p);
                }
            }
            // PV from private Plds (same-wave write->read, compiler inserts lgkmcnt)
            #pragma unroll
            for (int ks = 0; ks < 2; ++ks) {
                short8 pa = *(const short8*)&Plds[w][lr * 64 + ((ks * 32 + lh * 8) ^ ((lr & 7) << 3))];
                #pragma unroll
                for (int nt = 0; nt < 4; ++nt) {
                    short8 vb = *(const short8*)(Vb + (nt * 16 + lr) * 128 + ((ks * 64 + lh * 16) ^ rsw));
                    ctx[nt] = __builtin_amdgcn_mfma_f32_16x16x32_bf16(pa, vb, ctx[nt], 0, 0, 0);
                }
            }
        };

        short8 kE = Kt[tid],        vE = Vt8[tid];
        *(short8*)((char*)&Kbuf[0][0] + wphys) = kE;
        *(short8*)((char*)&Vbuf[0][0] + wphys) = vE;
        short8 kO = Kt[512 + tid],  vO = Vt8[512 + tid];
        __syncthreads();
        for (int c = 0; c < nchA; c += 2) {
            if (c + 2 < nchA) { kE = Kt[(c + 2) * 512 + tid]; vE = Vt8[(c + 2) * 512 + tid]; }
            if (c < mynch) p2((const char*)&Kbuf[0][0], (const char*)&Vbuf[0][0], c);
            if (c + 1 < nchA) {
                *(short8*)((char*)&Kbuf[1][0] + wphys) = kO;
                *(short8*)((char*)&Vbuf[1][0] + wphys) = vO;
            }
            __syncthreads();
            if (c + 1 < nchA) {
                if (c + 3 < nchA) { kO = Kt[(c + 3) * 512 + tid]; vO = Vt8[(c + 3) * 512 + tid]; }
                if (c + 1 < mynch) p2((const char*)&Kbuf[1][0], (const char*)&Vbuf[1][0], c + 1);
                if (c + 2 < nchA) {
                    *(short8*)((char*)&Kbuf[0][0] + wphys) = kE;
                    *(short8*)((char*)&Vbuf[0][0] + wphys) = vE;
                }
                __syncthreads();
            }
        }
    }

    // context stores: my 16 rows x full 64 cols
    #pragma unroll
    for (int nt = 0; nt < 4; ++nt)
        #pragma unroll
        for (int rr = 0; rr < 4; ++rr)
            ctx_out[((size_t)bh * S_LEN + qg_base + rr) * D_K + nt * 16 + lr] = ctx[nt][rr];

    // zero-fill fully-masked tail columns (total 31*64 cols x 64 rows per block -> balanced)
    {
        const float4 z = {0.f, 0.f, 0.f, 0.f};
        // long tile: cols >= nchA*64
        const int rowa = (31 - r) * 64 + (tid >> 3);
        float* rpa = attn_out + ((size_t)bh * S_LEN + rowa) * S_LEN;
        for (int k = nchA * KB + (tid & 7) * 4; k < S_LEN; k += 32)
            *(float4*)(rpa + k) = z;
        // short tile: cols >= nchB*64
        const int rowb = r * 64 + (tid >> 3);
        float* rpb = attn_out + ((size_t)bh * S_LEN + rowb) * S_LEN;
        for (int k = nchB * KB + (tid & 7) * 4; k < S_LEN; k += 32)
            *(float4*)(rpb + k) = z;
    }
}

// ===================== fallback (round-1 kernel, no ws) =====================
constexpr int LDP = 72;

__global__ __launch_bounds__(256)
void sdpa_fused_v1(const float* __restrict__ Q, const float* __restrict__ K,
                   const float* __restrict__ V, float* __restrict__ out)
{
    __shared__ __align__(16) unsigned short Klds[KB * LDP];
    __shared__ __align__(16) unsigned short Vtlds[D_K * LDP];
    __shared__ __align__(16) unsigned short Pl[4][16 * LDP];

    const int tid = threadIdx.x;
    const int w   = tid >> 6;
    const int l   = tid & 63;
    const int lr  = l & 15;
    const int lh  = l >> 4;

    const int bh   = blockIdx.y;
    const int qblk = (int)gridDim.x - 1 - (int)blockIdx.x;
    const int q0   = qblk * 64;
    const int qw   = q0 + w * 16;
    const int nchunks = qblk + 1;

    const size_t in_base = (size_t)bh * S_LEN * D_K;
    float* ctx_out  = out;
    float* attn_out = out + (size_t)N_BH * S_LEN * D_K;

    short8 qhi[2], qlo[2];
    {
        const float* qrow = Q + in_base + (size_t)(qw + lr) * D_K;
        #pragma unroll
        for (int ds = 0; ds < 2; ++ds) {
            const float4* p4 = (const float4*)(qrow + ds * 32 + lh * 8);
            float4 a = p4[0], b = p4[1];
            float x[8] = {a.x, a.y, a.z, a.w, b.x, b.y, b.z, b.w};
            short8 hi, lo;
            #pragma unroll
            for (int j = 0; j < 8; ++j) {
                unsigned short h = f2bf(x[j]);
                hi[j] = (short)h;
                lo[j] = (short)f2bf(x[j] - bf2f(h));
            }
            qhi[ds] = hi; qlo[ds] = lo;
        }
    }

    const int srow = tid >> 2;
    const int scol = (tid & 3) * 16;
    const float* kstage = K + in_base + (size_t)srow * D_K + scol;
    const float* vstage = V + in_base + (size_t)srow * D_K + scol;

    float inv_[4];
    {
        float sum[4] = {0.f, 0.f, 0.f, 0.f};
        for (int c = 0; c < nchunks; ++c) {
            {
                const float4* kp = (const float4*)(kstage + (size_t)c * KB * D_K);
                float4 a0 = kp[0], a1 = kp[1], a2 = kp[2], a3 = kp[3];
                float x[16] = {a0.x,a0.y,a0.z,a0.w, a1.x,a1.y,a1.z,a1.w,
                               a2.x,a2.y,a2.z,a2.w, a3.x,a3.y,a3.z,a3.w};
                short8 w0, w1;
                #pragma unroll
                for (int j = 0; j < 8; ++j) {
                    w0[j] = (short)f2bf(x[j]     * 0.125f);
                    w1[j] = (short)f2bf(x[j + 8] * 0.125f);
                }
                *(short8*)&Klds[srow * LDP + scol]     = w0;
                *(short8*)&Klds[srow * LDP + scol + 8] = w1;
            }
            __syncthreads();
            #pragma unroll
            for (int nt = 0; nt < 4; ++nt) {
                f32x4 acc = {0.f, 0.f, 0.f, 0.f};
                #pragma unroll
                for (int ks = 0; ks < 2; ++ks) {
                    short8 bk = *(const short8*)&Klds[(nt*16 + lr) * LDP + ks*32 + lh*8];
                    acc = __builtin_amdgcn_mfma_f32_16x16x32_bf16(qhi[ks], bk, acc, 0, 0, 0);
                    acc = __builtin_amdgcn_mfma_f32_16x16x32_bf16(qlo[ks], bk, acc, 0, 0, 0);
                }
                const int kg = c * KB + nt * 16 + lr;
                #pragma unroll
                for (int rr = 0; rr < 4; ++rr) {
                    if (kg <= qw + lh * 4 + rr)
                        sum[rr] += __expf(fminf(acc[rr], 60.f));
                }
            }
            __syncthreads();
        }
        #pragma unroll
        for (int rr = 0; rr < 4; ++rr) {
            float t = sum[rr];
            t += __shfl_xor(t, 1);
            t += __shfl_xor(t, 2);
            t += __shfl_xor(t, 4);
            t += __shfl_xor(t, 8);
            inv_[rr] = 1.f / t;
        }
    }

    f32x4 ctx[4];
    #pragma unroll
    for (int nt = 0; nt < 4; ++nt) ctx[nt] = (f32x4){0.f, 0.f, 0.f, 0.f};

    for (int c = 0; c < nchunks; ++c) {
        {
            const float4* kp = (const float4*)(kstage + (size_t)c * KB * D_K);
            float4 a0 = kp[0], a1 = kp[1], a2 = kp[2], a3 = kp[3];
            float x[16] = {a0.x,a0.y,a0.z,a0.w, a1.x,a1.y,a1.z,a1.w,
                           a2.x,a2.y,a2.z,a2.w, a3.x,a3.y,a3.z,a3.w};
            short8 w0, w1;
            #pragma unroll
            for (int j = 0; j < 8; ++j) {
                w0[j] = (short)f2bf(x[j]     * 0.125f);
                w1[j] = (short)f2bf(x[j + 8] * 0.125f);
            }
            *(short8*)&Klds[srow * LDP + scol]     = w0;
            *(short8*)&Klds[srow * LDP + scol + 8] = w1;

            const float4* vp = (const float4*)(vstage + (size_t)c * KB * D_K);
            float4 b0 = vp[0], b1 = vp[1], b2 = vp[2], b3 = vp[3];
            float y[16] = {b0.x,b0.y,b0.z,b0.w, b1.x,b1.y,b1.z,b1.w,
                           b2.x,b2.y,b2.z,b2.w, b3.x,b3.y,b3.z,b3.w};
            #pragma unroll
            for (int j = 0; j < 16; ++j)
                Vtlds[(scol + j) * LDP + srow] = f2bf(y[j]);
        }
        __syncthreads();

        #pragma unroll
        for (int nt = 0; nt < 4; ++nt) {
            f32x4 acc = {0.f, 0.f, 0.f, 0.f};
            #pragma unroll
            for (int ks = 0; ks < 2; ++ks) {
                short8 bk = *(const short8*)&Klds[(nt*16 + lr) * LDP + ks*32 + lh*8];
                acc = __builtin_amdgcn_mfma_f32_16x16x32_bf16(qhi[ks], bk, acc, 0, 0, 0);
                acc = __builtin_amdgcn_mfma_f32_16x16x32_bf16(qlo[ks], bk, acc, 0, 0, 0);
            }
            const int kg = c * KB + nt * 16 + lr;
            #pragma unroll
            for (int rr = 0; rr < 4; ++rr) {
                const int qg = qw + lh * 4 + rr;
                float p = (kg <= qg) ? __expf(fminf(acc[rr], 60.f)) * inv_[rr] : 0.f;
                attn_out[((size_t)bh * S_LEN + qg) * S_LEN + kg] = p;
                Pl[w][(lh * 4 + rr) * LDP + nt * 16 + lr] = f2bf(p);
            }
        }
        __syncthreads();

        #pragma unroll
        for (int ks = 0; ks < 2; ++ks) {
            short8 pa = *(const short8*)&Pl[w][lr * LDP + ks*32 + lh*8];
            #pragma unroll
            for (int nt = 0; nt < 4; ++nt) {
                short8 vb = *(const short8*)&Vtlds[(nt*16 + lr) * LDP + ks*32 + lh*8];
                ctx[nt] = __builtin_amdgcn_mfma_f32_16x16x32_bf16(pa, vb, ctx[nt], 0, 0, 0);
            }
        }
        __syncthreads();
    }

    #pragma unroll
    for (int nt = 0; nt < 4; ++nt)
        #pragma unroll
        for (int rr = 0; rr < 4; ++rr)
            ctx_out[((size_t)bh * S_LEN + qw + lh * 4 + rr) * D_K + nt * 16 + lr] = ctx[nt][rr];

    const int k0 = nchunks * KB;
    if (k0 < S_LEN) {
        const float4 z = {0.f, 0.f, 0.f, 0.f};
        for (int rr = 0; rr < 64; ++rr) {
            float* rowp = attn_out + ((size_t)bh * S_LEN + q0 + rr) * S_LEN;
            for (int k = k0 + tid * 4; k < S_LEN; k += 256 * 4)
                *(float4*)(rowp + k) = z;
        }
    }
}

extern "C" void kernel_launch(void* const* d_in, const int* in_sizes, int n_in,
                              void* d_out, int out_size, void* d_ws, size_t ws_size,
                              hipStream_t stream)
{
    const float* Q = (const float*)d_in[0];
    const float* K = (const float*)d_in[1];
    const float* V = (const float*)d_in[2];
    float* out = (float*)d_out;

    const size_t ws_needed = (size_t)2 * N_BH * S_LEN * D_K * sizeof(ushort_t);  // 16.8 MB
    if (ws_size >= ws_needed) {
        ushort_t* Kws = (ushort_t*)d_ws;
        ushort_t* Vws = Kws + (size_t)N_BH * S_LEN * D_K;
        prep_k<<<2048, 256, 0, stream>>>(K, Kws);
        prep_v<<<2048, 256, 0, stream>>>(V, Vws);
        sdpa_main<<<512, 512, 0, stream>>>(Q, Kws, Vws, out);
    } else {
        dim3 grid(S_LEN / 64, N_BH);
        sdpa_fused_v1<<<grid, 256, 0, stream>>>(Q, K, V, out);
    }
}

// Round 6
// 173.422 us; speedup vs baseline: 1.2362x; 1.0515x over previous
//
#include <hip/hip_runtime.h>

constexpr int S_LEN = 2048;
constexpr int D_K   = 64;
constexpr int N_BH  = 32;   // B*H
constexpr int KB    = 64;   // k per chunk

typedef __attribute__((ext_vector_type(8))) short short8;
typedef __attribute__((ext_vector_type(4))) float f32x4;
typedef unsigned short ushort_t;

__device__ __forceinline__ unsigned short f2bf(float f) {
    unsigned int u = __builtin_bit_cast(unsigned int, f);
    u += 0x7fffu + ((u >> 16) & 1u);          // round-to-nearest-even
    return (unsigned short)(u >> 16);
}
__device__ __forceinline__ float bf2f(unsigned short h) {
    unsigned int u = ((unsigned int)h) << 16;
    return __builtin_bit_cast(float, u);
}

// ============================ prep kernels ============================
__global__ __launch_bounds__(256)
void prep_k(const float* __restrict__ K, ushort_t* __restrict__ Kws) {
    const int idx = blockIdx.x * 256 + threadIdx.x;
    const float4* src = (const float4*)K + (size_t)idx * 2;
    float4 a = src[0], b = src[1];
    float x[8] = {a.x, a.y, a.z, a.w, b.x, b.y, b.z, b.w};
    short8 o;
    #pragma unroll
    for (int j = 0; j < 8; ++j) o[j] = (short)f2bf(x[j] * 0.125f);
    *(short8*)(Kws + (size_t)idx * 8) = o;
}

__global__ __launch_bounds__(256)
void prep_v(const float* __restrict__ V, ushort_t* __restrict__ Vws) {
    const int gid = blockIdx.x * 256 + threadIdx.x;
    const int u   = gid & 511;
    const int bc  = gid >> 9;
    const int c   = bc & 31;
    const int bh  = bc >> 5;
    const int kg  = u >> 6;
    const int d   = u & 63;
    const float* vp = V + ((size_t)bh * S_LEN + c * KB + kg * 8) * D_K + d;
    short8 o;
    #pragma unroll
    for (int i = 0; i < 8; ++i) o[i] = (short)f2bf(vp[(size_t)i * D_K]);
    *(short8*)(Vws + ((size_t)(bh * 32 + c) * D_K + d) * KB + kg * 8) = o;
}

// ============================ main kernel =============================
// 1024 blocks x 256 threads (4 waves). Each block: ONE 64-row q-tile.
// Co-resident CU slots get tiles {r, 15-r, 16+r, 31-r}: equal total work per CU
// but very different lengths -> pass-1 (compute) of some blocks overlaps
// pass-2 (write-bound) of others. Pass 1 uses single-bf16 QK (denominator only
// needs ~1e-2 rel accuracy); pass 2 keeps hi/lo split for the numerator.
// K/V LDS tiles [64][64] bf16, XOR-swizzled: byte = row*128 + (col ^ ((row&7)<<4)).
__global__ __launch_bounds__(256, 4)
void sdpa_main(const float* __restrict__ Q, const ushort_t* __restrict__ Kws,
               const ushort_t* __restrict__ Vws, float* __restrict__ out)
{
    __shared__ __align__(16) ushort_t Kbuf[2][4096];   // 16 KB
    __shared__ __align__(16) ushort_t Vbuf[2][4096];   // 16 KB
    __shared__ __align__(16) ushort_t Plds[4][1024];   //  8 KB (per-wave 16x64)

    const int tid = threadIdx.x;
    const int w   = tid >> 6;      // wave 0..3, owns 16 q rows
    const int l   = tid & 63;
    const int lr  = l & 15;
    const int lh  = l >> 4;

    // tile mapping: slots r=0..7 per group g; groups give t = r, 15-r, 16+r, 31-r
    const int bx  = blockIdx.x;    // 0..1023
    const int g   = bx >> 8;
    const int idx = bx & 255;
    const int bh  = idx >> 3;
    const int r   = idx & 7;
    int t;
    switch (g) {
        case 0:  t = r;      break;
        case 1:  t = 15 - r; break;
        case 2:  t = 16 + r; break;
        default: t = 31 - r; break;
    }
    const int nch = t + 1;
    const int q0  = t * 64;
    const int qg_base = q0 + w * 16 + lh * 4;    // + rr = this lane's q rows

    float* ctx_out  = out;                                   // [BH][S][D]
    float* attn_out = out + (size_t)N_BH * S_LEN * D_K;      // [BH][S][S]

    const short8* Kt  = (const short8*)(Kws + (size_t)bh * S_LEN * D_K);   // chunk c at c*512
    const short8* Vt8 = (const short8*)(Vws + (size_t)bh * 32 * 4096);

    // staging: thread writes units tid and tid+256 of each 512-unit chunk
    const int wrow0  = tid >> 3;                  // 0..31
    const int wcol   = (tid & 7) << 4;
    const int wphys0 = wrow0 * 128 + (wcol ^ ((wrow0 & 7) << 4));
    const int wphys1 = wphys0 + 32 * 128;         // rows 32..63, same (row&7)
    const int rsw    = (lr & 7) << 4;             // K/V frag-read swizzle (bytes)

    // ---- Q fragments for my 16 rows, hi/lo bf16 split ----
    short8 qhi[2], qlo[2];
    {
        const float* qrow = Q + ((size_t)bh * S_LEN + q0 + w * 16 + lr) * D_K;
        #pragma unroll
        for (int ds = 0; ds < 2; ++ds) {
            const float4* p4 = (const float4*)(qrow + ds * 32 + lh * 8);
            float4 a = p4[0], bq = p4[1];
            float x[8] = {a.x, a.y, a.z, a.w, bq.x, bq.y, bq.z, bq.w};
            short8 hi, lo;
            #pragma unroll
            for (int j = 0; j < 8; ++j) {
                unsigned short h = f2bf(x[j]);
                hi[j] = (short)h;
                lo[j] = (short)f2bf(x[j] - bf2f(h));
            }
            qhi[ds] = hi; qlo[ds] = lo;
        }
    }

    // ================= PASS 1: row sums (single-bf16 QK) =================
    float inv_[4];
    {
        float sum[4] = {0.f, 0.f, 0.f, 0.f};

        auto p1 = [&](const char* Kb, int c) {
            #pragma unroll
            for (int nt = 0; nt < 4; ++nt) {
                f32x4 acc = {0.f, 0.f, 0.f, 0.f};
                #pragma unroll
                for (int ks = 0; ks < 2; ++ks) {
                    short8 bk = *(const short8*)(Kb + (nt * 16 + lr) * 128 + ((ks * 64 + lh * 16) ^ rsw));
                    acc = __builtin_amdgcn_mfma_f32_16x16x32_bf16(qhi[ks], bk, acc, 0, 0, 0);
                }
                const int kg = c * KB + nt * 16 + lr;
                #pragma unroll
                for (int rr = 0; rr < 4; ++rr)
                    if (kg <= qg_base + rr) sum[rr] += __expf(fminf(acc[rr], 60.f));
            }
        };

        short8 kE0 = Kt[tid], kE1 = Kt[tid + 256];             // chunk 0
        *(short8*)((char*)&Kbuf[0][0] + wphys0) = kE0;
        *(short8*)((char*)&Kbuf[0][0] + wphys1) = kE1;
        short8 kO0 = Kt[512 + tid], kO1 = Kt[512 + tid + 256]; // chunk 1 (always in-bounds)
        __syncthreads();
        for (int c = 0; c < nch; c += 2) {
            if (c + 2 < nch) { kE0 = Kt[(c + 2) * 512 + tid]; kE1 = Kt[(c + 2) * 512 + tid + 256]; }
            p1((const char*)&Kbuf[0][0], c);
            if (c + 1 < nch) {
                *(short8*)((char*)&Kbuf[1][0] + wphys0) = kO0;
                *(short8*)((char*)&Kbuf[1][0] + wphys1) = kO1;
            }
            __syncthreads();
            if (c + 1 < nch) {
                if (c + 3 < nch) { kO0 = Kt[(c + 3) * 512 + tid]; kO1 = Kt[(c + 3) * 512 + tid + 256]; }
                p1((const char*)&Kbuf[1][0], c + 1);
                if (c + 2 < nch) {
                    *(short8*)((char*)&Kbuf[0][0] + wphys0) = kE0;
                    *(short8*)((char*)&Kbuf[0][0] + wphys1) = kE1;
                }
                __syncthreads();
            }
        }
        #pragma unroll
        for (int rr = 0; rr < 4; ++rr) {   // butterfly over the 16 col-lanes
            float s = sum[rr];
            s += __shfl_xor(s, 1);
            s += __shfl_xor(s, 2);
            s += __shfl_xor(s, 4);
            s += __shfl_xor(s, 8);
            inv_[rr] = 1.f / s;
        }
    }

    // ================= PASS 2: attn write + PV (hi/lo QK) =================
    f32x4 ctx[4];
    #pragma unroll
    for (int nt = 0; nt < 4; ++nt) ctx[nt] = (f32x4){0.f, 0.f, 0.f, 0.f};

    {
        auto p2 = [&](const char* Kb, const char* Vb, int c) {
            #pragma unroll
            for (int nt = 0; nt < 4; ++nt) {
                f32x4 acc = {0.f, 0.f, 0.f, 0.f};
                #pragma unroll
                for (int ks = 0; ks < 2; ++ks) {
                    short8 bk = *(const short8*)(Kb + (nt * 16 + lr) * 128 + ((ks * 64 + lh * 16) ^ rsw));
                    acc = __builtin_amdgcn_mfma_f32_16x16x32_bf16(qhi[ks], bk, acc, 0, 0, 0);
                    acc = __builtin_amdgcn_mfma_f32_16x16x32_bf16(qlo[ks], bk, acc, 0, 0, 0);
                }
                const int kg = c * KB + nt * 16 + lr;
                #pragma unroll
                for (int rr = 0; rr < 4; ++rr) {
                    const int pwr = lh * 4 + rr;
                    const int qg  = qg_base + rr;
                    float p = (kg <= qg) ? __expf(fminf(acc[rr], 60.f)) * inv_[rr] : 0.f;
                    attn_out[((size_t)bh * S_LEN + qg) * S_LEN + kg] = p;
                    Plds[w][pwr * 64 + ((nt * 16 + lr) ^ ((pwr & 7) << 3))] = f2bf(p);
                }
            }
            // PV from private Plds
            #pragma unroll
            for (int ks = 0; ks < 2; ++ks) {
                short8 pa = *(const short8*)&Plds[w][lr * 64 + ((ks * 32 + lh * 8) ^ ((lr & 7) << 3))];
                #pragma unroll
                for (int nt = 0; nt < 4; ++nt) {
                    short8 vb = *(const short8*)(Vb + (nt * 16 + lr) * 128 + ((ks * 64 + lh * 16) ^ rsw));
                    ctx[nt] = __builtin_amdgcn_mfma_f32_16x16x32_bf16(pa, vb, ctx[nt], 0, 0, 0);
                }
            }
        };

        short8 kE0 = Kt[tid],        kE1 = Kt[tid + 256];
        short8 vE0 = Vt8[tid],       vE1 = Vt8[tid + 256];
        *(short8*)((char*)&Kbuf[0][0] + wphys0) = kE0;
        *(short8*)((char*)&Kbuf[0][0] + wphys1) = kE1;
        *(short8*)((char*)&Vbuf[0][0] + wphys0) = vE0;
        *(short8*)((char*)&Vbuf[0][0] + wphys1) = vE1;
        short8 kO0 = Kt[512 + tid],  kO1 = Kt[512 + tid + 256];
        short8 vO0 = Vt8[512 + tid], vO1 = Vt8[512 + tid + 256];
        __syncthreads();
        for (int c = 0; c < nch; c += 2) {
            if (c + 2 < nch) {
                kE0 = Kt[(c + 2) * 512 + tid];  kE1 = Kt[(c + 2) * 512 + tid + 256];
                vE0 = Vt8[(c + 2) * 512 + tid]; vE1 = Vt8[(c + 2) * 512 + tid + 256];
            }
            p2((const char*)&Kbuf[0][0], (const char*)&Vbuf[0][0], c);
            if (c + 1 < nch) {
                *(short8*)((char*)&Kbuf[1][0] + wphys0) = kO0;
                *(short8*)((char*)&Kbuf[1][0] + wphys1) = kO1;
                *(short8*)((char*)&Vbuf[1][0] + wphys0) = vO0;
                *(short8*)((char*)&Vbuf[1][0] + wphys1) = vO1;
            }
            __syncthreads();
            if (c + 1 < nch) {
                if (c + 3 < nch) {
                    kO0 = Kt[(c + 3) * 512 + tid];  kO1 = Kt[(c + 3) * 512 + tid + 256];
                    vO0 = Vt8[(c + 3) * 512 + tid]; vO1 = Vt8[(c + 3) * 512 + tid + 256];
                }
                p2((const char*)&Kbuf[1][0], (const char*)&Vbuf[1][0], c + 1);
                if (c + 2 < nch) {
                    *(short8*)((char*)&Kbuf[0][0] + wphys0) = kE0;
                    *(short8*)((char*)&Kbuf[0][0] + wphys1) = kE1;
                    *(short8*)((char*)&Vbuf[0][0] + wphys0) = vE0;
                    *(short8*)((char*)&Vbuf[0][0] + wphys1) = vE1;
                }
                __syncthreads();
            }
        }
    }

    // context stores: my 16 rows x full 64 cols
    #pragma unroll
    for (int nt = 0; nt < 4; ++nt)
        #pragma unroll
        for (int rr = 0; rr < 4; ++rr)
            ctx_out[((size_t)bh * S_LEN + qg_base + rr) * D_K + nt * 16 + lr] = ctx[nt][rr];

    // zero-fill fully-masked tail columns (64 rows, 4 threads/row)
    const int k0 = nch * KB;
    if (k0 < S_LEN) {
        const float4 z = {0.f, 0.f, 0.f, 0.f};
        float* rowp = attn_out + ((size_t)bh * S_LEN + q0 + (tid >> 2)) * S_LEN;
        for (int k = k0 + (tid & 3) * 4; k < S_LEN; k += 16)
            *(float4*)(rowp + k) = z;
    }
}

// ===================== fallback (round-1 kernel, no ws) =====================
constexpr int LDP = 72;

__global__ __launch_bounds__(256)
void sdpa_fused_v1(const float* __restrict__ Q, const float* __restrict__ K,
                   const float* __restrict__ V, float* __restrict__ out)
{
    __shared__ __align__(16) unsigned short Klds[KB * LDP];
    __shared__ __align__(16) unsigned short Vtlds[D_K * LDP];
    __shared__ __align__(16) unsigned short Pl[4][16 * LDP];

    const int tid = threadIdx.x;
    const int w   = tid >> 6;
    const int l   = tid & 63;
    const int lr  = l & 15;
    const int lh  = l >> 4;

    const int bh   = blockIdx.y;
    const int qblk = (int)gridDim.x - 1 - (int)blockIdx.x;
    const int q0   = qblk * 64;
    const int qw   = q0 + w * 16;
    const int nchunks = qblk + 1;

    const size_t in_base = (size_t)bh * S_LEN * D_K;
    float* ctx_out  = out;
    float* attn_out = out + (size_t)N_BH * S_LEN * D_K;

    short8 qhi[2], qlo[2];
    {
        const float* qrow = Q + in_base + (size_t)(qw + lr) * D_K;
        #pragma unroll
        for (int ds = 0; ds < 2; ++ds) {
            const float4* p4 = (const float4*)(qrow + ds * 32 + lh * 8);
            float4 a = p4[0], b = p4[1];
            float x[8] = {a.x, a.y, a.z, a.w, b.x, b.y, b.z, b.w};
            short8 hi, lo;
            #pragma unroll
            for (int j = 0; j < 8; ++j) {
                unsigned short h = f2bf(x[j]);
                hi[j] = (short)h;
                lo[j] = (short)f2bf(x[j] - bf2f(h));
            }
            qhi[ds] = hi; qlo[ds] = lo;
        }
    }

    const int srow = tid >> 2;
    const int scol = (tid & 3) * 16;
    const float* kstage = K + in_base + (size_t)srow * D_K + scol;
    const float* vstage = V + in_base + (size_t)srow * D_K + scol;

    float inv_[4];
    {
        float sum[4] = {0.f, 0.f, 0.f, 0.f};
        for (int c = 0; c < nchunks; ++c) {
            {
                const float4* kp = (const float4*)(kstage + (size_t)c * KB * D_K);
                float4 a0 = kp[0], a1 = kp[1], a2 = kp[2], a3 = kp[3];
                float x[16] = {a0.x,a0.y,a0.z,a0.w, a1.x,a1.y,a1.z,a1.w,
                               a2.x,a2.y,a2.z,a2.w, a3.x,a3.y,a3.z,a3.w};
                short8 w0, w1;
                #pragma unroll
                for (int j = 0; j < 8; ++j) {
                    w0[j] = (short)f2bf(x[j]     * 0.125f);
                    w1[j] = (short)f2bf(x[j + 8] * 0.125f);
                }
                *(short8*)&Klds[srow * LDP + scol]     = w0;
                *(short8*)&Klds[srow * LDP + scol + 8] = w1;
            }
            __syncthreads();
            #pragma unroll
            for (int nt = 0; nt < 4; ++nt) {
                f32x4 acc = {0.f, 0.f, 0.f, 0.f};
                #pragma unroll
                for (int ks = 0; ks < 2; ++ks) {
                    short8 bk = *(const short8*)&Klds[(nt*16 + lr) * LDP + ks*32 + lh*8];
                    acc = __builtin_amdgcn_mfma_f32_16x16x32_bf16(qhi[ks], bk, acc, 0, 0, 0);
                    acc = __builtin_amdgcn_mfma_f32_16x16x32_bf16(qlo[ks], bk, acc, 0, 0, 0);
                }
                const int kg = c * KB + nt * 16 + lr;
                #pragma unroll
                for (int rr = 0; rr < 4; ++rr) {
                    if (kg <= qw + lh * 4 + rr)
                        sum[rr] += __expf(fminf(acc[rr], 60.f));
                }
            }
            __syncthreads();
        }
        #pragma unroll
        for (int rr = 0; rr < 4; ++rr) {
            float t = sum[rr];
            t += __shfl_xor(t, 1);
            t += __shfl_xor(t, 2);
            t += __shfl_xor(t, 4);
            t += __shfl_xor(t, 8);
            inv_[rr] = 1.f / t;
        }
    }

    f32x4 ctx[4];
    #pragma unroll
    for (int nt = 0; nt < 4; ++nt) ctx[nt] = (f32x4){0.f, 0.f, 0.f, 0.f};

    for (int c = 0; c < nchunks; ++c) {
        {
            const float4* kp = (const float4*)(kstage + (size_t)c * KB * D_K);
            float4 a0 = kp[0], a1 = kp[1], a2 = kp[2], a3 = kp[3];
            float x[16] = {a0.x,a0.y,a0.z,a0.w, a1.x,a1.y,a1.z,a1.w,
                           a2.x,a2.y,a2.z,a2.w, a3.x,a3.y,a3.z,a3.w};
            short8 w0, w1;
            #pragma unroll
            for (int j = 0; j < 8; ++j) {
                w0[j] = (short)f2bf(x[j]     * 0.125f);
                w1[j] = (short)f2bf(x[j + 8] * 0.125f);
            }
            *(short8*)&Klds[srow * LDP + scol]     = w0;
            *(short8*)&Klds[srow * LDP + scol + 8] = w1;

            const float4* vp = (const float4*)(vstage + (size_t)c * KB * D_K);
            float4 b0 = vp[0], b1 = vp[1], b2 = vp[2], b3 = vp[3];
            float y[16] = {b0.x,b0.y,b0.z,b0.w, b1.x,b1.y,b1.z,b1.w,
                           b2.x,b2.y,b2.z,b2.w, b3.x,b3.y,b3.z,b3.w};
            #pragma unroll
            for (int j = 0; j < 16; ++j)
                Vtlds[(scol + j) * LDP + srow] = f2bf(y[j]);
        }
        __syncthreads();

        #pragma unroll
        for (int nt = 0; nt < 4; ++nt) {
            f32x4 acc = {0.f, 0.f, 0.f, 0.f};
            #pragma unroll
            for (int ks = 0; ks < 2; ++ks) {
                short8 bk = *(const short8*)&Klds[(nt*16 + lr) * LDP + ks*32 + lh*8];
                acc = __builtin_amdgcn_mfma_f32_16x16x32_bf16(qhi[ks], bk, acc, 0, 0, 0);
                acc = __builtin_amdgcn_mfma_f32_16x16x32_bf16(qlo[ks], bk, acc, 0, 0, 0);
            }
            const int kg = c * KB + nt * 16 + lr;
            #pragma unroll
            for (int rr = 0; rr < 4; ++rr) {
                const int qg = qw + lh * 4 + rr;
                float p = (kg <= qg) ? __expf(fminf(acc[rr], 60.f)) * inv_[rr] : 0.f;
                attn_out[((size_t)bh * S_LEN + qg) * S_LEN + kg] = p;
                Pl[w][(lh * 4 + rr) * LDP + nt * 16 + lr] = f2bf(p);
            }
        }
        __syncthreads();

        #pragma unroll
        for (int ks = 0; ks < 2; ++ks) {
            short8 pa = *(const short8*)&Pl[w][lr * LDP + ks*32 + lh*8];
            #pragma unroll
            for (int nt = 0; nt < 4; ++nt) {
                short8 vb = *(const short8*)&Vtlds[(nt*16 + lr) * LDP + ks*32 + lh*8];
                ctx[nt] = __builtin_amdgcn_mfma_f32_16x16x32_bf16(pa, vb, ctx[nt], 0, 0, 0);
            }
        }
        __syncthreads();
    }

    #pragma unroll
    for (int nt = 0; nt < 4; ++nt)
        #pragma unroll
        for (int rr = 0; rr < 4; ++rr)
            ctx_out[((size_t)bh * S_LEN + qw + lh * 4 + rr) * D_K + nt * 16 + lr] = ctx[nt][rr];

    const int k0 = nchunks * KB;
    if (k0 < S_LEN) {
        const float4 z = {0.f, 0.f, 0.f, 0.f};
        for (int rr = 0; rr < 64; ++rr) {
            float* rowp = attn_out + ((size_t)bh * S_LEN + q0 + rr) * S_LEN;
            for (int k = k0 + tid * 4; k < S_LEN; k += 256 * 4)
                *(float4*)(rowp + k) = z;
        }
    }
}

extern "C" void kernel_launch(void* const* d_in, const int* in_sizes, int n_in,
                              void* d_out, int out_size, void* d_ws, size_t ws_size,
                              hipStream_t stream)
{
    const float* Q = (const float*)d_in[0];
    const float* K = (const float*)d_in[1];
    const float* V = (const float*)d_in[2];
    float* out = (float*)d_out;

    const size_t ws_needed = (size_t)2 * N_BH * S_LEN * D_K * sizeof(ushort_t);  // 16.8 MB
    if (ws_size >= ws_needed) {
        ushort_t* Kws = (ushort_t*)d_ws;
        ushort_t* Vws = Kws + (size_t)N_BH * S_LEN * D_K;
        prep_k<<<2048, 256, 0, stream>>>(K, Kws);
        prep_v<<<2048, 256, 0, stream>>>(V, Vws);
        sdpa_main<<<1024, 256, 0, stream>>>(Q, Kws, Vws, out);
    } else {
        dim3 grid(S_LEN / 64, N_BH);
        sdpa_fused_v1<<<grid, 256, 0, stream>>>(Q, K, V, out);
    }
}